// Round 1
// baseline (2933.212 us; speedup 1.0000x reference)
//
#include <hip/hip_runtime.h>

// Match numpy f32 semantics: no FMA contraction anywhere in this TU.
#pragma clang fp contract(off)

#define VWD 96
#define NVERT 2048
#define NFAC 512
#define NBATCH 8

// Each block: 256 threads = 4 waves; each wave owns one 4x4x4 voxel cube.
// LDS holds per-facet data for this batch: 5 float4 per facet (40 KB).
//   q0 = (bminx, bminy, bminz, bmaxx)
//   q1 = (bmaxy, bmaxz, det,   v3x)
//   q2 = (v3y,  v3z,  A00, A01)
//   q3 = (A02,  A10,  A11, A12)
//   q4 = (A20,  A21,  A22, 0)
__global__ __launch_bounds__(256) void voxelize_kernel(
    const float* __restrict__ vertices,
    const int*   __restrict__ facets,
    float*       __restrict__ out)
{
    __shared__ float4 lds[NFAC * 5];
    const int b = blockIdx.y;

    // ---- per-block facet precompute into LDS (2 facets per thread) ----
    {
        const float* vb = vertices + (size_t)b * NVERT * 3;
        for (int j = threadIdx.x; j < NFAC; j += 256) {
            int4 fi = ((const int4*)facets)[b * NFAC + j];
            float x0 = vb[3*fi.x+0], y0 = vb[3*fi.x+1], z0 = vb[3*fi.x+2];
            float x1 = vb[3*fi.y+0], y1 = vb[3*fi.y+1], z1 = vb[3*fi.y+2];
            float x2 = vb[3*fi.z+0], y2 = vb[3*fi.z+1], z2 = vb[3*fi.z+2];
            float x3 = vb[3*fi.w+0], y3 = vb[3*fi.w+1], z3 = vb[3*fi.w+2];
            // columns of M: v0-v3, v1-v3, v2-v3 (exact ref expression order)
            float a  = x0-x3, bb = x1-x3, c  = x2-x3;
            float d  = y0-y3, e  = y1-y3, f  = y2-y3;
            float g  = z0-z3, h  = z1-z3, ii = z2-z3;
            float A00 = e*ii - f*h,  A01 = c*h  - bb*ii, A02 = bb*f - c*e;
            float A10 = f*g  - d*ii, A11 = a*ii - c*g,   A12 = c*d  - a*f;
            float A20 = d*h  - e*g,  A21 = bb*g - a*h,   A22 = a*e  - bb*d;
            float det = a*(e*ii - f*h) - bb*(d*ii - f*g) + c*(d*h - e*g);
            // conservative bbox (margin >> rounded-lambda positional slop ~1e-6)
            float bminx = fminf(fminf(x0,x1),fminf(x2,x3)) - 1e-4f;
            float bminy = fminf(fminf(y0,y1),fminf(y2,y3)) - 1e-4f;
            float bminz = fminf(fminf(z0,z1),fminf(z2,z3)) - 1e-4f;
            float bmaxx = fmaxf(fmaxf(x0,x1),fmaxf(x2,x3)) + 1e-4f;
            float bmaxy = fmaxf(fmaxf(y0,y1),fmaxf(y2,y3)) + 1e-4f;
            float bmaxz = fmaxf(fmaxf(z0,z1),fmaxf(z2,z3)) + 1e-4f;
            lds[j*5+0] = make_float4(bminx, bminy, bminz, bmaxx);
            lds[j*5+1] = make_float4(bmaxy, bmaxz, det,   x3);
            lds[j*5+2] = make_float4(y3,    z3,    A00,   A01);
            lds[j*5+3] = make_float4(A02,   A10,   A11,   A12);
            lds[j*5+4] = make_float4(A20,   A21,   A22,   0.0f);
        }
    }
    __syncthreads();

    // ---- wave -> 4x4x4 cube mapping ----
    const int wave = threadIdx.x >> 6;
    const int lane = threadIdx.x & 63;
    const int cube = blockIdx.x * 4 + wave;          // 0 .. 13823
    const int cz  = cube % 24;
    const int cyx = cube / 24;
    const int cy  = cyx % 24;
    const int cx  = cyx / 24;
    const int iz = cz*4 + (lane & 3);
    const int iy = cy*4 + ((lane >> 2) & 3);
    const int ix = cx*4 + (lane >> 4);

    // grid point (exact-numerator, correctly-rounded division == jnp f32)
    const float px = (float)(2*ix + 1 - VWD) / 96.0f;
    const float py = (float)(2*iy + 1 - VWD) / 96.0f;
    const float pz = (float)(2*iz + 1 - VWD) / 96.0f;

    // wave-uniform cube bounds (cell centers)
    const float cMinX = (float)(2*(cx*4)   + 1 - VWD) / 96.0f;
    const float cMaxX = (float)(2*(cx*4+3) + 1 - VWD) / 96.0f;
    const float cMinY = (float)(2*(cy*4)   + 1 - VWD) / 96.0f;
    const float cMaxY = (float)(2*(cy*4+3) + 1 - VWD) / 96.0f;
    const float cMinZ = (float)(2*(cz*4)   + 1 - VWD) / 96.0f;
    const float cMaxZ = (float)(2*(cz*4+3) + 1 - VWD) / 96.0f;

    bool found = false;
    for (int fct = 0; fct < NFAC; ++fct) {
        float4 q0 = lds[fct*5+0];
        float4 q1 = lds[fct*5+1];
        // wave-uniform bbox reject
        if (cMaxX < q0.x || cMinX > q0.w ||
            cMaxY < q0.y || cMinY > q1.x ||
            cMaxZ < q0.z || cMinZ > q1.y) continue;
        float4 q2 = lds[fct*5+2];
        float4 q3 = lds[fct*5+3];
        float4 q4 = lds[fct*5+4];
        float det = q1.z;
        float dx = px - q1.w;
        float dy = py - q2.x;
        float dz = pz - q2.y;
        // left-assoc dot products, true f32 division (matches ref rounding)
        float n0 = q2.z*dx + q2.w*dy + q3.x*dz;
        float n1 = q3.y*dx + q3.z*dy + q3.w*dz;
        float n2 = q4.x*dx + q4.y*dy + q4.z*dz;
        float l0 = n0 / det;
        float l1 = n1 / det;
        float l2 = n2 / det;
        float l3 = 1.0f - (l0 + l1 + l2);
        bool inside = (l0 >= 0.0f) & (l0 <= 1.0f) &
                      (l1 >= 0.0f) & (l1 <= 1.0f) &
                      (l2 >= 0.0f) & (l2 <= 1.0f) &
                      (l3 >= 0.0f) & (l3 <= 1.0f);
        if (inside) { found = true; break; }
    }

    out[(size_t)b * (VWD*VWD*VWD) + (size_t)ix*(VWD*VWD) + iy*VWD + iz]
        = found ? 1.0f : 0.0f;
}

extern "C" void kernel_launch(void* const* d_in, const int* in_sizes, int n_in,
                              void* d_out, int out_size, void* d_ws, size_t ws_size,
                              hipStream_t stream) {
    const float* vertices = (const float*)d_in[0];   // (8, 2048, 3) f32
    const int*   facets   = (const int*)d_in[1];     // (8, 512, 4) int
    float*       out      = (float*)d_out;           // (8, 96, 96, 96) f32

    dim3 grid(3456, NBATCH);   // 3456 blocks * 4 waves = 13824 cubes per batch
    voxelize_kernel<<<grid, 256, 0, stream>>>(vertices, facets, out);
}